// Round 6
// baseline (635.500 us; speedup 1.0000x reference)
//
#include <hip/hip_runtime.h>

// GNN (5 layers sparse msg-passing + dense+relu) -> gather -> concat -> FC over 50000 entities.
// CSR built once per call (hist + distributed scan + scatter).
// Fused layer kernel: wave-per-row aggregate into swizzled LDS bf16 tile -> MFMA -> relu -> bf16.
// PING-PONG node buffers across layers (fused agg reads arbitrary rows; in-place update races).
// FC: 64n-tile LDS-staged (swizzled), b-split grid, operand-swapped MFMA for float4 stores.

#define N_NODES 50000
#define N_EDGES 800000
#define D 128
#define N_LAYERS 5
#define N_ENT 50000
#define BATCH 1024
#define KDIM 256  // 2*D
#define SCAN_BLOCKS ((N_NODES + 255) / 256)  // 196
#define FC_NT 64

typedef __attribute__((ext_vector_type(8))) __bf16 bf16x8;
typedef __attribute__((ext_vector_type(4))) float f32x4;
typedef __attribute__((ext_vector_type(8))) unsigned short u16x8;
typedef __attribute__((ext_vector_type(4))) unsigned short u16x4;

__device__ inline unsigned short f2bf(float x) {
  unsigned int u = __float_as_uint(x);
  unsigned int r = (u + 0x7FFFu + ((u >> 16) & 1u)) >> 16;  // RNE
  return (unsigned short)r;
}
__device__ inline float bf2f(unsigned short b) {
  return __uint_as_float(((unsigned int)b) << 16);
}

__global__ void zero_i32(int* __restrict__ p, int n) {
  int i = blockIdx.x * blockDim.x + threadIdx.x;
  if (i < n) p[i] = 0;
}

__global__ void hist_kernel(const int* __restrict__ rows, int* __restrict__ counts) {
  int i = blockIdx.x * blockDim.x + threadIdx.x;
  int stride = gridDim.x * blockDim.x;
  for (; i < N_EDGES; i += stride) atomicAdd(&counts[rows[i]], 1);
}

__device__ inline int block_exscan256(int v, int* wsum, int* tot) {
  int t = threadIdx.x, lane = t & 63, wid = t >> 6;
  int s = v;
#pragma unroll
  for (int off = 1; off < 64; off <<= 1) {
    int u = __shfl_up(s, off, 64);
    if (lane >= off) s += u;
  }
  if (lane == 63) wsum[wid] = s;
  __syncthreads();
  if (t == 0) {
    int run = 0;
#pragma unroll
    for (int w = 0; w < 4; ++w) { int tmp = wsum[w]; wsum[w] = run; run += tmp; }
    wsum[4] = run;
  }
  __syncthreads();
  *tot = wsum[4];
  return wsum[wid] + s - v;
}

__global__ __launch_bounds__(256) void scan1_kernel(const int* __restrict__ counts,
                                                    int* __restrict__ row_ptr,
                                                    int* __restrict__ bsum) {
  __shared__ int wsum[5];
  int i = blockIdx.x * 256 + threadIdx.x;
  int v = (i < N_NODES) ? counts[i] : 0;
  int tot;
  int ex = block_exscan256(v, wsum, &tot);
  if (i < N_NODES) row_ptr[i] = ex;
  if (threadIdx.x == 0) bsum[blockIdx.x] = tot;
}

__global__ __launch_bounds__(256) void scan2_kernel(int* __restrict__ bsum) {
  __shared__ int wsum[5];
  int t = threadIdx.x;
  int v = (t < SCAN_BLOCKS) ? bsum[t] : 0;
  int tot;
  int ex = block_exscan256(v, wsum, &tot);
  if (t < SCAN_BLOCKS) bsum[t] = ex;
}

__global__ __launch_bounds__(256) void scan3_kernel(const int* __restrict__ counts,
                                                    const int* __restrict__ bsum,
                                                    int* __restrict__ row_ptr,
                                                    int* __restrict__ cursor) {
  int i = blockIdx.x * 256 + threadIdx.x;
  if (i >= N_NODES) return;
  int ex = row_ptr[i] + bsum[blockIdx.x];
  row_ptr[i] = ex;
  cursor[i] = ex;
  if (i == N_NODES - 1) row_ptr[N_NODES] = ex + counts[i];
}

__global__ void scatter_kernel(const int* __restrict__ rows, const int* __restrict__ cols,
                               const float* __restrict__ vals, int* __restrict__ cursor,
                               int* __restrict__ col_s, float* __restrict__ val_s) {
  int i = blockIdx.x * blockDim.x + threadIdx.x;
  int stride = gridDim.x * blockDim.x;
  for (; i < N_EDGES; i += stride) {
    int r = rows[i];
    int pos = atomicAdd(&cursor[r], 1);
    col_s[pos] = cols[i];
    val_s[pos] = vals[i];
  }
}

__global__ __launch_bounds__(256) void tobf16_kernel(const float* __restrict__ src,
                                                     unsigned short* __restrict__ dst,
                                                     int n8) {
  int i = blockIdx.x * blockDim.x + threadIdx.x;
  if (i >= n8) return;
  float4 a = *(const float4*)&src[i * 8];
  float4 b = *(const float4*)&src[i * 8 + 4];
  u16x8 o;
  o[0] = f2bf(a.x); o[1] = f2bf(a.y); o[2] = f2bf(a.z); o[3] = f2bf(a.w);
  o[4] = f2bf(b.x); o[5] = f2bf(b.y); o[6] = f2bf(b.z); o[7] = f2bf(b.w);
  *(u16x8*)&dst[i * 8] = o;
}

// gnn_W [L][k][j] f32 -> Wt5 [L][j][k] bf16
__global__ void wconv_kernel(const float* __restrict__ gW, unsigned short* __restrict__ Wt5) {
  int idx = blockIdx.x * 256 + threadIdx.x;
  if (idx >= N_LAYERS * D * D) return;
  int l = idx / (D * D);
  int rem = idx - l * D * D;
  int j = rem >> 7;
  int k = rem & 127;
  Wt5[idx] = f2bf(gW[l * D * D + k * D + j]);
}

// Fused GNN layer: block = 64 node rows. READS xb, WRITES yb (must be distinct buffers!).
// Phase 1: wave w aggregates rows w*16..w*16+15 -> swizzled bf16 LDS tile [64][128].
// Phase 2: Y[r][j] = relu(sum_k agg[r][k] * Wt[j][k] + b[j]) via MFMA, A=W (rows j),
//          B=agg (cols r) so lanes hold 4 consecutive j -> ushort4 stores.
__global__ __launch_bounds__(256) void layer_fused(const unsigned short* __restrict__ xb,
                                                   const int* __restrict__ row_ptr,
                                                   const int* __restrict__ cols,
                                                   const float* __restrict__ vals,
                                                   const unsigned short* __restrict__ Bt,  // [j][k]
                                                   const float* __restrict__ bias,
                                                   unsigned short* __restrict__ yb) {
  __shared__ unsigned short atile[64 * D];  // 16 KB, 16B-chunk swizzle: chunk ^= row&7
  int t = threadIdx.x, lane = t & 63, wave = t >> 6;
  int r0 = blockIdx.x * 64;
  char* ab = (char*)atile;

  // ---- phase 1: aggregate ----
  for (int rr = 0; rr < 16; ++rr) {
    int r = r0 + wave * 16 + rr;
    if (r < N_NODES) {
      int e0 = row_ptr[r], e1 = row_ptr[r + 1];
      float ax = 0.f, ay = 0.f;
      for (int base = e0; base < e1; base += 64) {
        int idx = base + lane;
        bool ok = idx < e1;
        int cl = ok ? cols[idx] : 0;
        float vl = ok ? vals[idx] : 0.f;
        int cnt = min(64, e1 - base);
        int j = 0;
        for (; j + 8 <= cnt; j += 8) {
          int c[8]; float v[8]; ushort2 xv[8];
#pragma unroll
          for (int q = 0; q < 8; ++q) { c[q] = __shfl(cl, j + q); v[q] = __shfl(vl, j + q); }
#pragma unroll
          for (int q = 0; q < 8; ++q) xv[q] = *(const ushort2*)&xb[c[q] * D + lane * 2];
#pragma unroll
          for (int q = 0; q < 8; ++q) {
            ax = fmaf(v[q], bf2f(xv[q].x), ax);
            ay = fmaf(v[q], bf2f(xv[q].y), ay);
          }
        }
        for (; j < cnt; ++j) {
          int c = __shfl(cl, j); float v = __shfl(vl, j);
          ushort2 xv0 = *(const ushort2*)&xb[c * D + lane * 2];
          ax = fmaf(v, bf2f(xv0.x), ax);
          ay = fmaf(v, bf2f(xv0.y), ay);
        }
      }
      int row_l = wave * 16 + rr;
      // lane writes elems lane*2, lane*2+1: chunk = lane>>2, within-chunk = (lane&3)*4
      char* dst = ab + row_l * 256 + ((((lane >> 2) ^ (row_l & 7)) << 4) | ((lane & 3) << 2));
      ushort2 o = {f2bf(ax), f2bf(ay)};
      *(ushort2*)dst = o;
    }
  }
  __syncthreads();

  // ---- phase 2: GEMM + relu ----
  int l16 = lane & 15, lq = lane >> 4;
  f32x4 acc[4][2];
#pragma unroll
  for (int m = 0; m < 4; ++m) { acc[m][0] = (f32x4){0,0,0,0}; acc[m][1] = (f32x4){0,0,0,0}; }
#pragma unroll
  for (int kk = 0; kk < 4; ++kk) {
    bf16x8 wfr[2];
#pragma unroll
    for (int nt = 0; nt < 2; ++nt)
      wfr[nt] = *(const bf16x8*)&Bt[(wave * 32 + nt * 16 + l16) * D + kk * 32 + lq * 8];
#pragma unroll
    for (int m = 0; m < 4; ++m) {
      int row_l = m * 16 + l16;
      bf16x8 afr = *(const bf16x8*)(ab + row_l * 256 + ((((kk * 4 + lq) ^ (row_l & 7)) << 4)));
      acc[m][0] = __builtin_amdgcn_mfma_f32_16x16x32_bf16(wfr[0], afr, acc[m][0], 0, 0, 0);
      acc[m][1] = __builtin_amdgcn_mfma_f32_16x16x32_bf16(wfr[1], afr, acc[m][1], 0, 0, 0);
    }
  }
  // lane holds (m,nt): j = wave*32 + nt*16 + lq*4 + reg, r = r0 + m*16 + l16
#pragma unroll
  for (int nt = 0; nt < 2; ++nt) {
    int jb = wave * 32 + nt * 16 + lq * 4;
    float4 bb = *(const float4*)&bias[jb];
#pragma unroll
    for (int m = 0; m < 4; ++m) {
      int r = r0 + m * 16 + l16;
      if (r < N_NODES) {
        u16x4 o;
        o[0] = f2bf(fmaxf(acc[m][nt][0] + bb.x, 0.f));
        o[1] = f2bf(fmaxf(acc[m][nt][1] + bb.y, 0.f));
        o[2] = f2bf(fmaxf(acc[m][nt][2] + bb.z, 0.f));
        o[3] = f2bf(fmaxf(acc[m][nt][3] + bb.w, 0.f));
        *(u16x4*)&yb[(size_t)r * D + jb] = o;
      }
    }
  }
}

// transpose+convert fc_W [KDIM][N_ENT] f32 -> Wt [N_ENT][KDIM] bf16
__global__ __launch_bounds__(256) void wt_kernel(const float* __restrict__ fcW,
                                                 unsigned short* __restrict__ Wt) {
  int n = blockIdx.x * 256 + threadIdx.x;
  int k0 = blockIdx.y * 8;
  if (n >= N_ENT) return;
  u16x8 pk;
#pragma unroll
  for (int e = 0; e < 8; ++e) pk[e] = f2bf(fcW[(size_t)(k0 + e) * N_ENT + n]);
  *(u16x8*)&Wt[(size_t)n * KDIM + k0] = pk;
}

__global__ __launch_bounds__(256) void gather_bf16(const unsigned short* __restrict__ xb,
                                                   const float* __restrict__ rel_table,
                                                   const int* __restrict__ head_idx,
                                                   const int* __restrict__ rel_ids,
                                                   unsigned short* __restrict__ ebf) {
  int b = blockIdx.x;
  int k = threadIdx.x;
  unsigned short v;
  if (k < D) v = xb[head_idx[b] * D + k];
  else       v = f2bf(rel_table[rel_ids[b] * D + (k - D)]);
  ebf[b * KDIM + k] = v;
}

// FC: out[b][n] = sum_k ebf[b][k]*Wt[n][k] + fcb[n]
// grid (782, 4): n-tile 64 (LDS-staged swizzled, 32 KB), b-range 256 = 4 chunks of 64.
// Operand-swapped MFMA: D[row=n][col=b] -> lane holds 4 consecutive n -> float4 stores.
__global__ __launch_bounds__(256) void fc_mfma(const unsigned short* __restrict__ ebf,
                                               const unsigned short* __restrict__ Wt,
                                               const float* __restrict__ fcb,
                                               float* __restrict__ out) {
  __shared__ unsigned short wtile[FC_NT * KDIM];  // 32 KB
  int t = threadIdx.x;
  int lane = t & 63, wave = t >> 6;
  int l16 = lane & 15, lq = lane >> 4;
  int n0 = blockIdx.x * FC_NT;

  // stage Wt[n0..n0+63][:] -> LDS, 16B-chunk swizzle: chunk ^= (row & 7); 32 chunks/row
  const char* wsrc = (const char*)(Wt + (size_t)n0 * KDIM);
  char* wdst = (char*)wtile;
#pragma unroll
  for (int it = 0; it < 8; ++it) {
    int c = it * 256 + t;  // 16B chunk id, 0..2047
    int row = c >> 5;
    int ci = c & 31;
    float4 v = *(const float4*)(wsrc + (size_t)c * 16);
    *(float4*)(wdst + row * 512 + ((ci ^ (row & 7)) * 16)) = v;
  }
  __syncthreads();

  int nrow = wave * 16 + l16;          // local A-frag row (n)
  int n_st = n0 + wave * 16 + lq * 4;  // store col base (4 consecutive n in regs)
  bool nok = n_st < N_ENT;             // N_ENT % 4 == 0: all-or-nothing per lane
  float4 bv = {0.f, 0.f, 0.f, 0.f};
  if (nok) bv = *(const float4*)&fcb[n_st];

#pragma unroll
  for (int bc = 0; bc < 4; ++bc) {
    int b0 = blockIdx.y * 256 + bc * 64;
    f32x4 acc[4];
#pragma unroll
    for (int m = 0; m < 4; ++m) acc[m] = (f32x4){0.f, 0.f, 0.f, 0.f};
#pragma unroll
    for (int kk = 0; kk < 8; ++kk) {
      bf16x8 afr = *(const bf16x8*)(wdst + nrow * 512 + (((4 * kk + lq) ^ (nrow & 7)) * 16));
#pragma unroll
      for (int m = 0; m < 4; ++m) {
        bf16x8 bfr = *(const bf16x8*)&ebf[(b0 + m * 16 + l16) * KDIM + kk * 32 + lq * 8];
        acc[m] = __builtin_amdgcn_mfma_f32_16x16x32_bf16(afr, bfr, acc[m], 0, 0, 0);
      }
    }
    if (nok) {
#pragma unroll
      for (int m = 0; m < 4; ++m) {
        int b = b0 + m * 16 + l16;
        float4 o = {acc[m][0] + bv.x, acc[m][1] + bv.y, acc[m][2] + bv.z, acc[m][3] + bv.w};
        *(float4*)&out[(size_t)b * N_ENT + n_st] = o;
      }
    }
  }
}

extern "C" void kernel_launch(void* const* d_in, const int* in_sizes, int n_in,
                              void* d_out, int out_size, void* d_ws, size_t ws_size,
                              hipStream_t stream) {
  const float* entity    = (const float*)d_in[0];
  const float* edge_val  = (const float*)d_in[1];
  const float* gnn_W     = (const float*)d_in[2];
  const float* gnn_b     = (const float*)d_in[3];
  const float* rel_table = (const float*)d_in[4];
  const float* fc_W      = (const float*)d_in[5];
  const float* fc_b      = (const float*)d_in[6];
  const int* edge_row    = (const int*)d_in[7];
  const int* edge_col    = (const int*)d_in[8];
  const int* head_idx    = (const int*)d_in[9];
  const int* rel_ids     = (const int*)d_in[10];
  float* out = (float*)d_out;

  char* ws = (char*)d_ws;
  size_t off = 0;
  auto alloc = [&](size_t bytes) -> void* {
    void* p = ws + off;
    off = (off + bytes + 255) & ~(size_t)255;
    return p;
  };
  int* counts   = (int*)alloc((size_t)N_NODES * 4);
  int* row_ptr  = (int*)alloc((size_t)(N_NODES + 1) * 4);
  int* cursor   = (int*)alloc((size_t)N_NODES * 4);
  int* bsum     = (int*)alloc((size_t)256 * 4);
  int* col_s    = (int*)alloc((size_t)N_EDGES * 4);
  float* val_s  = (float*)alloc((size_t)N_EDGES * 4);
  unsigned short* xA    = (unsigned short*)alloc((size_t)N_NODES * D * 2);
  unsigned short* xB    = (unsigned short*)alloc((size_t)N_NODES * D * 2);
  unsigned short* entbf = (unsigned short*)alloc((size_t)N_NODES * D * 2);
  unsigned short* ebf   = (unsigned short*)alloc((size_t)BATCH * KDIM * 2);
  unsigned short* Wt    = (unsigned short*)alloc((size_t)(N_ENT + 64) * KDIM * 2);  // +64 rows pad
  unsigned short* Wt5   = (unsigned short*)alloc((size_t)N_LAYERS * D * D * 2);

  // CSR build (row structure is layer-invariant)
  zero_i32<<<(N_NODES + 255) / 256, 256, 0, stream>>>(counts, N_NODES);
  hist_kernel<<<1024, 256, 0, stream>>>(edge_row, counts);
  scan1_kernel<<<SCAN_BLOCKS, 256, 0, stream>>>(counts, row_ptr, bsum);
  scan2_kernel<<<1, 256, 0, stream>>>(bsum);
  scan3_kernel<<<SCAN_BLOCKS, 256, 0, stream>>>(counts, bsum, row_ptr, cursor);
  scatter_kernel<<<1024, 256, 0, stream>>>(edge_row, edge_col, edge_val, cursor, col_s, val_s);

  // conversions
  tobf16_kernel<<<(N_NODES * D / 8 + 255) / 256, 256, 0, stream>>>(entity, entbf, N_NODES * D / 8);
  wconv_kernel<<<(N_LAYERS * D * D + 255) / 256, 256, 0, stream>>>(gnn_W, Wt5);

  // 5 fused GNN layers, ping-pong buffers (fused kernel must not update in place)
  // layer0: entbf->xA, layer1: xA->xB, layer2: xB->xA, layer3: xA->xB, layer4: xB->xA
  for (int layer = 0; layer < N_LAYERS; ++layer) {
    const unsigned short* xin = (layer == 0) ? entbf : ((layer & 1) ? xA : xB);
    unsigned short* yout = (layer & 1) ? xB : xA;
    layer_fused<<<(N_NODES + 63) / 64, 256, 0, stream>>>(xin, row_ptr, col_s, val_s,
                                                         Wt5 + (size_t)layer * D * D,
                                                         gnn_b + (size_t)layer * D, yout);
  }

  // FC weight transpose + embed gather (final features in xA)
  dim3 wtg((N_ENT + 255) / 256, KDIM / 8);
  wt_kernel<<<wtg, 256, 0, stream>>>(fc_W, Wt);
  gather_bf16<<<BATCH, KDIM, 0, stream>>>(xA, rel_table, head_idx, rel_ids, ebf);

  // FC: grid (n-tiles, b-splits)
  dim3 fcg((N_ENT + FC_NT - 1) / FC_NT, BATCH / 256);
  fc_mfma<<<fcg, 256, 0, stream>>>(ebf, Wt, fc_b, out);
}

// Round 7
// 552.479 us; speedup vs baseline: 1.1503x; 1.1503x over previous
//
#include <hip/hip_runtime.h>

// GNN (5 layers sparse msg-passing + dense+relu) -> gather -> concat -> FC over 50000 entities.
// CSR built once per call (hist + distributed scan + scatter).
// layer_fused v2: quarter-wave aggregation (16B/lane full-row gathers, 4 rows in flight/wave)
//   -> swizzled LDS bf16 tile -> operand-swapped MFMA -> relu -> bf16. Ping-pong buffers.
// fc v5: NO LDS. Wt fragments (b-invariant under operand swap) held in registers for the
//   whole block; ebf B-frags from L2; float4 stores. b-split 2.

#define N_NODES 50000
#define N_EDGES 800000
#define D 128
#define N_LAYERS 5
#define N_ENT 50000
#define BATCH 1024
#define KDIM 256  // 2*D
#define SCAN_BLOCKS ((N_NODES + 255) / 256)  // 196
#define FC_NT 64

typedef __attribute__((ext_vector_type(8))) __bf16 bf16x8;
typedef __attribute__((ext_vector_type(4))) float f32x4;
typedef __attribute__((ext_vector_type(8))) unsigned short u16x8;
typedef __attribute__((ext_vector_type(4))) unsigned short u16x4;

__device__ inline unsigned short f2bf(float x) {
  unsigned int u = __float_as_uint(x);
  unsigned int r = (u + 0x7FFFu + ((u >> 16) & 1u)) >> 16;  // RNE
  return (unsigned short)r;
}
__device__ inline float bf2f(unsigned short b) {
  return __uint_as_float(((unsigned int)b) << 16);
}

__global__ void zero_i32(int* __restrict__ p, int n) {
  int i = blockIdx.x * blockDim.x + threadIdx.x;
  if (i < n) p[i] = 0;
}

__global__ void hist_kernel(const int* __restrict__ rows, int* __restrict__ counts) {
  int i = blockIdx.x * blockDim.x + threadIdx.x;
  int stride = gridDim.x * blockDim.x;
  for (; i < N_EDGES; i += stride) atomicAdd(&counts[rows[i]], 1);
}

__device__ inline int block_exscan256(int v, int* wsum, int* tot) {
  int t = threadIdx.x, lane = t & 63, wid = t >> 6;
  int s = v;
#pragma unroll
  for (int off = 1; off < 64; off <<= 1) {
    int u = __shfl_up(s, off, 64);
    if (lane >= off) s += u;
  }
  if (lane == 63) wsum[wid] = s;
  __syncthreads();
  if (t == 0) {
    int run = 0;
#pragma unroll
    for (int w = 0; w < 4; ++w) { int tmp = wsum[w]; wsum[w] = run; run += tmp; }
    wsum[4] = run;
  }
  __syncthreads();
  *tot = wsum[4];
  return wsum[wid] + s - v;
}

__global__ __launch_bounds__(256) void scan1_kernel(const int* __restrict__ counts,
                                                    int* __restrict__ row_ptr,
                                                    int* __restrict__ bsum) {
  __shared__ int wsum[5];
  int i = blockIdx.x * 256 + threadIdx.x;
  int v = (i < N_NODES) ? counts[i] : 0;
  int tot;
  int ex = block_exscan256(v, wsum, &tot);
  if (i < N_NODES) row_ptr[i] = ex;
  if (threadIdx.x == 0) bsum[blockIdx.x] = tot;
}

__global__ __launch_bounds__(256) void scan2_kernel(int* __restrict__ bsum) {
  __shared__ int wsum[5];
  int t = threadIdx.x;
  int v = (t < SCAN_BLOCKS) ? bsum[t] : 0;
  int tot;
  int ex = block_exscan256(v, wsum, &tot);
  if (t < SCAN_BLOCKS) bsum[t] = ex;
}

__global__ __launch_bounds__(256) void scan3_kernel(const int* __restrict__ counts,
                                                    const int* __restrict__ bsum,
                                                    int* __restrict__ row_ptr,
                                                    int* __restrict__ cursor) {
  int i = blockIdx.x * 256 + threadIdx.x;
  if (i >= N_NODES) return;
  int ex = row_ptr[i] + bsum[blockIdx.x];
  row_ptr[i] = ex;
  cursor[i] = ex;
  if (i == N_NODES - 1) row_ptr[N_NODES] = ex + counts[i];
}

__global__ void scatter_kernel(const int* __restrict__ rows, const int* __restrict__ cols,
                               const float* __restrict__ vals, int* __restrict__ cursor,
                               int* __restrict__ col_s, float* __restrict__ val_s) {
  int i = blockIdx.x * blockDim.x + threadIdx.x;
  int stride = gridDim.x * blockDim.x;
  for (; i < N_EDGES; i += stride) {
    int r = rows[i];
    int pos = atomicAdd(&cursor[r], 1);
    col_s[pos] = cols[i];
    val_s[pos] = vals[i];
  }
}

__global__ __launch_bounds__(256) void tobf16_kernel(const float* __restrict__ src,
                                                     unsigned short* __restrict__ dst,
                                                     int n8) {
  int i = blockIdx.x * blockDim.x + threadIdx.x;
  if (i >= n8) return;
  float4 a = *(const float4*)&src[i * 8];
  float4 b = *(const float4*)&src[i * 8 + 4];
  u16x8 o;
  o[0] = f2bf(a.x); o[1] = f2bf(a.y); o[2] = f2bf(a.z); o[3] = f2bf(a.w);
  o[4] = f2bf(b.x); o[5] = f2bf(b.y); o[6] = f2bf(b.z); o[7] = f2bf(b.w);
  *(u16x8*)&dst[i * 8] = o;
}

// gnn_W [L][k][j] f32 -> Wt5 [L][j][k] bf16
__global__ void wconv_kernel(const float* __restrict__ gW, unsigned short* __restrict__ Wt5) {
  int idx = blockIdx.x * 256 + threadIdx.x;
  if (idx >= N_LAYERS * D * D) return;
  int l = idx / (D * D);
  int rem = idx - l * D * D;
  int j = rem >> 7;
  int k = rem & 127;
  Wt5[idx] = f2bf(gW[l * D * D + k * D + j]);
}

// Fused GNN layer: block = 64 node rows. READS xb, WRITES yb (distinct buffers!).
// Phase 1 (quarter-wave): lane (q,l16) handles row r = r0 + w*16 + p*4 + q over 4 passes;
//   16 lanes cover the full 128-d row (8 bf16 = 16B per lane per gather). Edge (col,val)
//   loaded 16-wide per quarter, shfl-broadcast, 4 gathers deep.
// Phase 2: Y[r][j] = relu(sum_k agg[r][k]*Wt[j][k] + b[j]), A=W rows j, B=agg cols r,
//   lanes hold 4 consecutive j -> ushort4 stores.
__global__ __launch_bounds__(256) void layer_fused(const unsigned short* __restrict__ xb,
                                                   const int* __restrict__ row_ptr,
                                                   const int* __restrict__ cols,
                                                   const float* __restrict__ vals,
                                                   const unsigned short* __restrict__ Bt,  // [j][k]
                                                   const float* __restrict__ bias,
                                                   unsigned short* __restrict__ yb) {
  __shared__ unsigned short atile[64 * D];  // 16 KB; 16B chunks, chunk ^= row&7
  int t = threadIdx.x, lane = t & 63, wave = t >> 6;
  int q = lane >> 4, l16 = lane & 15;
  int r0 = blockIdx.x * 64;
  char* ab = (char*)atile;

  // ---- phase 1: aggregate (4 rows per wave-pass, 4 passes) ----
#pragma unroll
  for (int p = 0; p < 4; ++p) {
    int row_l = wave * 16 + p * 4 + q;
    int r = r0 + row_l;
    float acc[8] = {0.f, 0.f, 0.f, 0.f, 0.f, 0.f, 0.f, 0.f};
    if (r < N_NODES) {
      int e0 = row_ptr[r], e1 = row_ptr[r + 1];
      for (int base = e0; base < e1; base += 16) {
        // 16 edges loaded lane-parallel within the quarter
        int idx = base + l16;
        bool ok = idx < e1;
        int cl = ok ? cols[idx] : 0;
        float vl = ok ? vals[idx] : 0.f;
        int cnt = min(16, e1 - base);
        int j = 0;
        for (; j + 4 <= cnt; j += 4) {
          int c[4]; float v[4]; u16x8 xv[4];
#pragma unroll
          for (int u = 0; u < 4; ++u) {
            c[u] = __shfl(cl, q * 16 + j + u);
            v[u] = __shfl(vl, q * 16 + j + u);
          }
#pragma unroll
          for (int u = 0; u < 4; ++u) xv[u] = *(const u16x8*)&xb[c[u] * D + l16 * 8];
#pragma unroll
          for (int u = 0; u < 4; ++u)
#pragma unroll
            for (int dd = 0; dd < 8; ++dd) acc[dd] = fmaf(v[u], bf2f(xv[u][dd]), acc[dd]);
        }
        for (; j < cnt; ++j) {
          int c = __shfl(cl, q * 16 + j);
          float v = __shfl(vl, q * 16 + j);
          u16x8 xv0 = *(const u16x8*)&xb[c * D + l16 * 8];
#pragma unroll
          for (int dd = 0; dd < 8; ++dd) acc[dd] = fmaf(v, bf2f(xv0[dd]), acc[dd]);
        }
      }
    }
    // write row chunk: chunk index = l16, swizzled by row
    u16x8 o;
#pragma unroll
    for (int dd = 0; dd < 8; ++dd) o[dd] = f2bf(acc[dd]);
    *(u16x8*)(ab + row_l * 256 + ((l16 ^ (row_l & 7)) << 4)) = o;
  }
  __syncthreads();

  // ---- phase 2: GEMM + relu ----
  int lq = lane >> 4;
  f32x4 acc2[4][2];
#pragma unroll
  for (int m = 0; m < 4; ++m) { acc2[m][0] = (f32x4){0,0,0,0}; acc2[m][1] = (f32x4){0,0,0,0}; }
#pragma unroll
  for (int kk = 0; kk < 4; ++kk) {
    bf16x8 wfr[2];
#pragma unroll
    for (int nt = 0; nt < 2; ++nt)
      wfr[nt] = *(const bf16x8*)&Bt[(wave * 32 + nt * 16 + l16) * D + kk * 32 + lq * 8];
#pragma unroll
    for (int m = 0; m < 4; ++m) {
      int row_l = m * 16 + l16;
      bf16x8 afr = *(const bf16x8*)(ab + row_l * 256 + ((((kk * 4 + lq) ^ (row_l & 7)) << 4)));
      acc2[m][0] = __builtin_amdgcn_mfma_f32_16x16x32_bf16(wfr[0], afr, acc2[m][0], 0, 0, 0);
      acc2[m][1] = __builtin_amdgcn_mfma_f32_16x16x32_bf16(wfr[1], afr, acc2[m][1], 0, 0, 0);
    }
  }
#pragma unroll
  for (int nt = 0; nt < 2; ++nt) {
    int jb = wave * 32 + nt * 16 + lq * 4;
    float4 bb = *(const float4*)&bias[jb];
#pragma unroll
    for (int m = 0; m < 4; ++m) {
      int r = r0 + m * 16 + l16;
      if (r < N_NODES) {
        u16x4 o;
        o[0] = f2bf(fmaxf(acc2[m][nt][0] + bb.x, 0.f));
        o[1] = f2bf(fmaxf(acc2[m][nt][1] + bb.y, 0.f));
        o[2] = f2bf(fmaxf(acc2[m][nt][2] + bb.z, 0.f));
        o[3] = f2bf(fmaxf(acc2[m][nt][3] + bb.w, 0.f));
        *(u16x4*)&yb[(size_t)r * D + jb] = o;
      }
    }
  }
}

// transpose+convert fc_W [KDIM][N_ENT] f32 -> Wt [N_ENT][KDIM] bf16
__global__ __launch_bounds__(256) void wt_kernel(const float* __restrict__ fcW,
                                                 unsigned short* __restrict__ Wt) {
  int n = blockIdx.x * 256 + threadIdx.x;
  int k0 = blockIdx.y * 8;
  if (n >= N_ENT) return;
  u16x8 pk;
#pragma unroll
  for (int e = 0; e < 8; ++e) pk[e] = f2bf(fcW[(size_t)(k0 + e) * N_ENT + n]);
  *(u16x8*)&Wt[(size_t)n * KDIM + k0] = pk;
}

__global__ __launch_bounds__(256) void gather_bf16(const unsigned short* __restrict__ xb,
                                                   const float* __restrict__ rel_table,
                                                   const int* __restrict__ head_idx,
                                                   const int* __restrict__ rel_ids,
                                                   unsigned short* __restrict__ ebf) {
  int b = blockIdx.x;
  int k = threadIdx.x;
  unsigned short v;
  if (k < D) v = xb[head_idx[b] * D + k];
  else       v = f2bf(rel_table[rel_ids[b] * D + (k - D)]);
  ebf[b * KDIM + k] = v;
}

// FC: out[b][n] = sum_k ebf[b][k]*Wt[n][k] + fcb[n]
// grid (782, 2). NO LDS: afr (Wt rows, b-invariant) loaded once into registers per block;
// loop 8 b-chunks of 64; ebf B-frags from L2; operand-swapped MFMA -> float4 stores.
__global__ __launch_bounds__(256) void fc_mfma(const unsigned short* __restrict__ ebf,
                                               const unsigned short* __restrict__ Wt,
                                               const float* __restrict__ fcb,
                                               float* __restrict__ out) {
  int t = threadIdx.x;
  int lane = t & 63, wave = t >> 6;
  int l16 = lane & 15, lq = lane >> 4;
  int n0 = blockIdx.x * FC_NT;

  int nrow = n0 + wave * 16 + l16;  // Wt row this lane reads (pad rows allocated past N_ENT)
  const unsigned short* wp = Wt + (size_t)nrow * KDIM + lq * 8;
  bf16x8 afr[8];
#pragma unroll
  for (int kk = 0; kk < 8; ++kk) afr[kk] = *(const bf16x8*)(wp + kk * 32);

  int n_st = n0 + wave * 16 + lq * 4;  // store col base (4 consecutive n in regs)
  bool nok = n_st < N_ENT;             // N_ENT % 4 == 0: all-or-nothing per lane
  float4 bv = {0.f, 0.f, 0.f, 0.f};
  if (nok) bv = *(const float4*)&fcb[n_st];

#pragma unroll
  for (int bc = 0; bc < 8; ++bc) {
    int b0 = blockIdx.y * 512 + bc * 64;
    f32x4 acc[4];
#pragma unroll
    for (int m = 0; m < 4; ++m) acc[m] = (f32x4){0.f, 0.f, 0.f, 0.f};
#pragma unroll
    for (int kk = 0; kk < 8; ++kk) {
#pragma unroll
      for (int m = 0; m < 4; ++m) {
        bf16x8 bfr = *(const bf16x8*)&ebf[(b0 + m * 16 + l16) * KDIM + kk * 32 + lq * 8];
        acc[m] = __builtin_amdgcn_mfma_f32_16x16x32_bf16(afr[kk], bfr, acc[m], 0, 0, 0);
      }
    }
    if (nok) {
#pragma unroll
      for (int m = 0; m < 4; ++m) {
        int b = b0 + m * 16 + l16;
        float4 o = {acc[m][0] + bv.x, acc[m][1] + bv.y, acc[m][2] + bv.z, acc[m][3] + bv.w};
        *(float4*)&out[(size_t)b * N_ENT + n_st] = o;
      }
    }
  }
}

extern "C" void kernel_launch(void* const* d_in, const int* in_sizes, int n_in,
                              void* d_out, int out_size, void* d_ws, size_t ws_size,
                              hipStream_t stream) {
  const float* entity    = (const float*)d_in[0];
  const float* edge_val  = (const float*)d_in[1];
  const float* gnn_W     = (const float*)d_in[2];
  const float* gnn_b     = (const float*)d_in[3];
  const float* rel_table = (const float*)d_in[4];
  const float* fc_W      = (const float*)d_in[5];
  const float* fc_b      = (const float*)d_in[6];
  const int* edge_row    = (const int*)d_in[7];
  const int* edge_col    = (const int*)d_in[8];
  const int* head_idx    = (const int*)d_in[9];
  const int* rel_ids     = (const int*)d_in[10];
  float* out = (float*)d_out;

  char* ws = (char*)d_ws;
  size_t off = 0;
  auto alloc = [&](size_t bytes) -> void* {
    void* p = ws + off;
    off = (off + bytes + 255) & ~(size_t)255;
    return p;
  };
  int* counts   = (int*)alloc((size_t)N_NODES * 4);
  int* row_ptr  = (int*)alloc((size_t)(N_NODES + 1) * 4);
  int* cursor   = (int*)alloc((size_t)N_NODES * 4);
  int* bsum     = (int*)alloc((size_t)256 * 4);
  int* col_s    = (int*)alloc((size_t)N_EDGES * 4);
  float* val_s  = (float*)alloc((size_t)N_EDGES * 4);
  unsigned short* xA    = (unsigned short*)alloc((size_t)N_NODES * D * 2);
  unsigned short* xB    = (unsigned short*)alloc((size_t)N_NODES * D * 2);
  unsigned short* entbf = (unsigned short*)alloc((size_t)N_NODES * D * 2);
  unsigned short* ebf   = (unsigned short*)alloc((size_t)BATCH * KDIM * 2);
  unsigned short* Wt    = (unsigned short*)alloc((size_t)(N_ENT + 64) * KDIM * 2);  // +64 rows pad
  unsigned short* Wt5   = (unsigned short*)alloc((size_t)N_LAYERS * D * D * 2);

  // CSR build (row structure is layer-invariant)
  zero_i32<<<(N_NODES + 255) / 256, 256, 0, stream>>>(counts, N_NODES);
  hist_kernel<<<1024, 256, 0, stream>>>(edge_row, counts);
  scan1_kernel<<<SCAN_BLOCKS, 256, 0, stream>>>(counts, row_ptr, bsum);
  scan2_kernel<<<1, 256, 0, stream>>>(bsum);
  scan3_kernel<<<SCAN_BLOCKS, 256, 0, stream>>>(counts, bsum, row_ptr, cursor);
  scatter_kernel<<<1024, 256, 0, stream>>>(edge_row, edge_col, edge_val, cursor, col_s, val_s);

  // conversions
  tobf16_kernel<<<(N_NODES * D / 8 + 255) / 256, 256, 0, stream>>>(entity, entbf, N_NODES * D / 8);
  wconv_kernel<<<(N_LAYERS * D * D + 255) / 256, 256, 0, stream>>>(gnn_W, Wt5);

  // 5 fused GNN layers, ping-pong buffers
  // layer0: entbf->xA, layer1: xA->xB, layer2: xB->xA, layer3: xA->xB, layer4: xB->xA
  for (int layer = 0; layer < N_LAYERS; ++layer) {
    const unsigned short* xin = (layer == 0) ? entbf : ((layer & 1) ? xA : xB);
    unsigned short* yout = (layer & 1) ? xB : xA;
    layer_fused<<<(N_NODES + 63) / 64, 256, 0, stream>>>(xin, row_ptr, col_s, val_s,
                                                         Wt5 + (size_t)layer * D * D,
                                                         gnn_b + (size_t)layer * D, yout);
  }

  // FC weight transpose + embed gather (final features in xA)
  dim3 wtg((N_ENT + 255) / 256, KDIM / 8);
  wt_kernel<<<wtg, 256, 0, stream>>>(fc_W, Wt);
  gather_bf16<<<BATCH, KDIM, 0, stream>>>(xA, rel_table, head_idx, rel_ids, ebf);

  // FC: grid (n-tiles, b-halves)
  dim3 fcg((N_ENT + FC_NT - 1) / FC_NT, 2);
  fc_mfma<<<fcg, 256, 0, stream>>>(ebf, Wt, fc_b, out);
}

// Round 9
// 401.175 us; speedup vs baseline: 1.5841x; 1.3772x over previous
//
#include <hip/hip_runtime.h>

// GNN (5 layers sparse msg-passing + dense+relu) -> gather -> concat -> FC over 50000 entities.
// CSR built once per call (hist + distributed scan + scatter).
// layer_fused: quarter-wave aggregation -> swizzled LDS bf16 tile -> swapped MFMA -> relu.
// fc v7: ebf b-chunk staged to LDS coalesced (kills L2 16B-sector amplification),
//   swizzle ci^((row&7)<<2) (2-way, free), Wt A-frags register-resident, float4 stores.

#define N_NODES 50000
#define N_EDGES 800000
#define D 128
#define N_LAYERS 5
#define N_ENT 50000
#define BATCH 1024
#define KDIM 256  // 2*D
#define SCAN_BLOCKS ((N_NODES + 255) / 256)  // 196
#define FC_NT 128  // n-tile per block (wave: 32 n)

typedef __attribute__((ext_vector_type(8))) __bf16 bf16x8;
typedef __attribute__((ext_vector_type(4))) float f32x4;
typedef __attribute__((ext_vector_type(8))) unsigned short u16x8;
typedef __attribute__((ext_vector_type(4))) unsigned short u16x4;

__device__ inline unsigned short f2bf(float x) {
  unsigned int u = __float_as_uint(x);
  unsigned int r = (u + 0x7FFFu + ((u >> 16) & 1u)) >> 16;  // RNE
  return (unsigned short)r;
}
__device__ inline float bf2f(unsigned short b) {
  return __uint_as_float(((unsigned int)b) << 16);
}

__global__ void zero_i32(int* __restrict__ p, int n) {
  int i = blockIdx.x * blockDim.x + threadIdx.x;
  if (i < n) p[i] = 0;
}

__global__ void hist_kernel(const int* __restrict__ rows, int* __restrict__ counts) {
  int i = blockIdx.x * blockDim.x + threadIdx.x;
  int stride = gridDim.x * blockDim.x;
  for (; i < N_EDGES; i += stride) atomicAdd(&counts[rows[i]], 1);
}

__device__ inline int block_exscan256(int v, int* wsum, int* tot) {
  int t = threadIdx.x, lane = t & 63, wid = t >> 6;
  int s = v;
#pragma unroll
  for (int off = 1; off < 64; off <<= 1) {
    int u = __shfl_up(s, off, 64);
    if (lane >= off) s += u;
  }
  if (lane == 63) wsum[wid] = s;
  __syncthreads();
  if (t == 0) {
    int run = 0;
#pragma unroll
    for (int w = 0; w < 4; ++w) { int tmp = wsum[w]; wsum[w] = run; run += tmp; }
    wsum[4] = run;
  }
  __syncthreads();
  *tot = wsum[4];
  return wsum[wid] + s - v;
}

__global__ __launch_bounds__(256) void scan1_kernel(const int* __restrict__ counts,
                                                    int* __restrict__ row_ptr,
                                                    int* __restrict__ bsum) {
  __shared__ int wsum[5];
  int i = blockIdx.x * 256 + threadIdx.x;
  int v = (i < N_NODES) ? counts[i] : 0;
  int tot;
  int ex = block_exscan256(v, wsum, &tot);
  if (i < N_NODES) row_ptr[i] = ex;
  if (threadIdx.x == 0) bsum[blockIdx.x] = tot;
}

__global__ __launch_bounds__(256) void scan2_kernel(int* __restrict__ bsum) {
  __shared__ int wsum[5];
  int t = threadIdx.x;
  int v = (t < SCAN_BLOCKS) ? bsum[t] : 0;
  int tot;
  int ex = block_exscan256(v, wsum, &tot);
  if (t < SCAN_BLOCKS) bsum[t] = ex;
}

__global__ __launch_bounds__(256) void scan3_kernel(const int* __restrict__ counts,
                                                    const int* __restrict__ bsum,
                                                    int* __restrict__ row_ptr,
                                                    int* __restrict__ cursor) {
  int i = blockIdx.x * 256 + threadIdx.x;
  if (i >= N_NODES) return;
  int ex = row_ptr[i] + bsum[blockIdx.x];
  row_ptr[i] = ex;
  cursor[i] = ex;
  if (i == N_NODES - 1) row_ptr[N_NODES] = ex + counts[i];
}

__global__ void scatter_kernel(const int* __restrict__ rows, const int* __restrict__ cols,
                               const float* __restrict__ vals, int* __restrict__ cursor,
                               int* __restrict__ col_s, float* __restrict__ val_s) {
  int i = blockIdx.x * blockDim.x + threadIdx.x;
  int stride = gridDim.x * blockDim.x;
  for (; i < N_EDGES; i += stride) {
    int r = rows[i];
    int pos = atomicAdd(&cursor[r], 1);
    col_s[pos] = cols[i];
    val_s[pos] = vals[i];
  }
}

__global__ __launch_bounds__(256) void tobf16_kernel(const float* __restrict__ src,
                                                     unsigned short* __restrict__ dst,
                                                     int n8) {
  int i = blockIdx.x * blockDim.x + threadIdx.x;
  if (i >= n8) return;
  float4 a = *(const float4*)&src[i * 8];
  float4 b = *(const float4*)&src[i * 8 + 4];
  u16x8 o;
  o[0] = f2bf(a.x); o[1] = f2bf(a.y); o[2] = f2bf(a.z); o[3] = f2bf(a.w);
  o[4] = f2bf(b.x); o[5] = f2bf(b.y); o[6] = f2bf(b.z); o[7] = f2bf(b.w);
  *(u16x8*)&dst[i * 8] = o;
}

// gnn_W [L][k][j] f32 -> Wt5 [L][j][k] bf16
__global__ void wconv_kernel(const float* __restrict__ gW, unsigned short* __restrict__ Wt5) {
  int idx = blockIdx.x * 256 + threadIdx.x;
  if (idx >= N_LAYERS * D * D) return;
  int l = idx / (D * D);
  int rem = idx - l * D * D;
  int j = rem >> 7;
  int k = rem & 127;
  Wt5[idx] = f2bf(gW[l * D * D + k * D + j]);
}

// Fused GNN layer: block = 64 node rows. READS xb, WRITES yb (distinct buffers!).
__global__ __launch_bounds__(256) void layer_fused(const unsigned short* __restrict__ xb,
                                                   const int* __restrict__ row_ptr,
                                                   const int* __restrict__ cols,
                                                   const float* __restrict__ vals,
                                                   const unsigned short* __restrict__ Bt,  // [j][k]
                                                   const float* __restrict__ bias,
                                                   unsigned short* __restrict__ yb) {
  __shared__ unsigned short atile[64 * D];  // 16 KB; 16B chunks, chunk ^= row&7 (16 chunks/row)
  int t = threadIdx.x, lane = t & 63, wave = t >> 6;
  int q = lane >> 4, l16 = lane & 15;
  int r0 = blockIdx.x * 64;
  char* ab = (char*)atile;

  // ---- phase 1: aggregate (4 rows per wave-pass, 4 passes) ----
#pragma unroll
  for (int p = 0; p < 4; ++p) {
    int row_l = wave * 16 + p * 4 + q;
    int r = r0 + row_l;
    float acc[8] = {0.f, 0.f, 0.f, 0.f, 0.f, 0.f, 0.f, 0.f};
    if (r < N_NODES) {
      int e0 = row_ptr[r], e1 = row_ptr[r + 1];
      for (int base = e0; base < e1; base += 16) {
        int idx = base + l16;
        bool ok = idx < e1;
        int cl = ok ? cols[idx] : 0;
        float vl = ok ? vals[idx] : 0.f;
        int cnt = min(16, e1 - base);
        int j = 0;
        for (; j + 4 <= cnt; j += 4) {
          int c[4]; float v[4]; u16x8 xv[4];
#pragma unroll
          for (int u = 0; u < 4; ++u) {
            c[u] = __shfl(cl, q * 16 + j + u);
            v[u] = __shfl(vl, q * 16 + j + u);
          }
#pragma unroll
          for (int u = 0; u < 4; ++u) xv[u] = *(const u16x8*)&xb[c[u] * D + l16 * 8];
#pragma unroll
          for (int u = 0; u < 4; ++u)
#pragma unroll
            for (int dd = 0; dd < 8; ++dd) acc[dd] = fmaf(v[u], bf2f(xv[u][dd]), acc[dd]);
        }
        for (; j < cnt; ++j) {
          int c = __shfl(cl, q * 16 + j);
          float v = __shfl(vl, q * 16 + j);
          u16x8 xv0 = *(const u16x8*)&xb[c * D + l16 * 8];
#pragma unroll
          for (int dd = 0; dd < 8; ++dd) acc[dd] = fmaf(v, bf2f(xv0[dd]), acc[dd]);
        }
      }
    }
    u16x8 o;
#pragma unroll
    for (int dd = 0; dd < 8; ++dd) o[dd] = f2bf(acc[dd]);
    *(u16x8*)(ab + row_l * 256 + ((l16 ^ (row_l & 7)) << 4)) = o;
  }
  __syncthreads();

  // ---- phase 2: GEMM + relu ----
  int lq = lane >> 4;
  f32x4 acc2[4][2];
#pragma unroll
  for (int m = 0; m < 4; ++m) { acc2[m][0] = (f32x4){0,0,0,0}; acc2[m][1] = (f32x4){0,0,0,0}; }
#pragma unroll
  for (int kk = 0; kk < 4; ++kk) {
    bf16x8 wfr[2];
#pragma unroll
    for (int nt = 0; nt < 2; ++nt)
      wfr[nt] = *(const bf16x8*)&Bt[(wave * 32 + nt * 16 + l16) * D + kk * 32 + lq * 8];
#pragma unroll
    for (int m = 0; m < 4; ++m) {
      int row_l = m * 16 + l16;
      bf16x8 afr = *(const bf16x8*)(ab + row_l * 256 + ((((kk * 4 + lq) ^ (row_l & 7)) << 4)));
      acc2[m][0] = __builtin_amdgcn_mfma_f32_16x16x32_bf16(wfr[0], afr, acc2[m][0], 0, 0, 0);
      acc2[m][1] = __builtin_amdgcn_mfma_f32_16x16x32_bf16(wfr[1], afr, acc2[m][1], 0, 0, 0);
    }
  }
#pragma unroll
  for (int nt = 0; nt < 2; ++nt) {
    int jb = wave * 32 + nt * 16 + lq * 4;
    float4 bb = *(const float4*)&bias[jb];
#pragma unroll
    for (int m = 0; m < 4; ++m) {
      int r = r0 + m * 16 + l16;
      if (r < N_NODES) {
        u16x4 o;
        o[0] = f2bf(fmaxf(acc2[m][nt][0] + bb.x, 0.f));
        o[1] = f2bf(fmaxf(acc2[m][nt][1] + bb.y, 0.f));
        o[2] = f2bf(fmaxf(acc2[m][nt][2] + bb.z, 0.f));
        o[3] = f2bf(fmaxf(acc2[m][nt][3] + bb.w, 0.f));
        *(u16x4*)&yb[(size_t)r * D + jb] = o;
      }
    }
  }
}

// transpose+convert fc_W [KDIM][N_ENT] f32 -> Wt [N_ENT][KDIM] bf16
__global__ __launch_bounds__(256) void wt_kernel(const float* __restrict__ fcW,
                                                 unsigned short* __restrict__ Wt) {
  int n = blockIdx.x * 256 + threadIdx.x;
  int k0 = blockIdx.y * 8;
  if (n >= N_ENT) return;
  u16x8 pk;
#pragma unroll
  for (int e = 0; e < 8; ++e) pk[e] = f2bf(fcW[(size_t)(k0 + e) * N_ENT + n]);
  *(u16x8*)&Wt[(size_t)n * KDIM + k0] = pk;
}

__global__ __launch_bounds__(256) void gather_bf16(const unsigned short* __restrict__ xb,
                                                   const float* __restrict__ rel_table,
                                                   const int* __restrict__ head_idx,
                                                   const int* __restrict__ rel_ids,
                                                   unsigned short* __restrict__ ebf) {
  int b = blockIdx.x;
  int k = threadIdx.x;
  unsigned short v;
  if (k < D) v = xb[head_idx[b] * D + k];
  else       v = f2bf(rel_table[rel_ids[b] * D + (k - D)]);
  ebf[b * KDIM + k] = v;
}

// FC: out[b][n] = sum_k ebf[b][k]*Wt[n][k] + fcb[n]
// grid (392, 2): n-tile 128 (wave: 32 n), b-half 512 = 8 chunks of 64.
// Per bc: stage ebf[64b][256k] -> LDS (COALESCED 16B/thread, swizzle ci^((row&7)<<2)),
// Wt A-frags (b-invariant) register-resident; swapped MFMA; float4 stores.
__global__ __launch_bounds__(256, 2) void fc_mfma(const unsigned short* __restrict__ ebf,
                                                  const unsigned short* __restrict__ Wt,
                                                  const float* __restrict__ fcb,
                                                  float* __restrict__ out) {
  __shared__ unsigned short etile[64 * KDIM];  // 32 KB
  int t = threadIdx.x;
  int lane = t & 63, wave = t >> 6;
  int l16 = lane & 15, lq = lane >> 4;
  int n0 = blockIdx.x * FC_NT;
  char* eb = (char*)etile;

  // Wt A-frags for this wave's 32 n: [nt][kk], held whole kernel (pad rows alloc'd past N_ENT)
  bf16x8 afr[2][8];
#pragma unroll
  for (int nt = 0; nt < 2; ++nt) {
    const unsigned short* wp = Wt + (size_t)(n0 + wave * 32 + nt * 16 + l16) * KDIM + lq * 8;
#pragma unroll
    for (int kk = 0; kk < 8; ++kk) afr[nt][kk] = *(const bf16x8*)(wp + kk * 32);
  }

  int n_st[2]; float4 bv[2];
#pragma unroll
  for (int nt = 0; nt < 2; ++nt) {
    n_st[nt] = n0 + wave * 32 + nt * 16 + lq * 4;
    bv[nt] = make_float4(0.f, 0.f, 0.f, 0.f);
    if (n_st[nt] < N_ENT) bv[nt] = *(const float4*)&fcb[n_st[nt]];
  }

  for (int bc = 0; bc < 8; ++bc) {
    int b0 = blockIdx.y * 512 + bc * 64;
    // stage ebf[b0..b0+63][:] -> LDS; 2048 chunks of 16B, coalesced reads
    const char* esrc = (const char*)(ebf + (size_t)b0 * KDIM);
#pragma unroll
    for (int it = 0; it < 8; ++it) {
      int c = it * 256 + t;
      int row = c >> 5;        // 32 chunks (512 B) per row
      int ci = c & 31;
      float4 v = *(const float4*)(esrc + (size_t)c * 16);
      *(float4*)(eb + row * 512 + ((ci ^ ((row & 7) << 2)) << 4)) = v;
    }
    __syncthreads();

    f32x4 acc[2][4];
#pragma unroll
    for (int nt = 0; nt < 2; ++nt)
#pragma unroll
      for (int m = 0; m < 4; ++m) acc[nt][m] = (f32x4){0.f, 0.f, 0.f, 0.f};

#pragma unroll
    for (int m = 0; m < 4; ++m) {
      int row = m * 16 + l16;
#pragma unroll
      for (int kk = 0; kk < 8; ++kk) {
        bf16x8 bfr = *(const bf16x8*)(eb + row * 512 + ((((kk * 4 + lq) ^ ((row & 7) << 2)) << 4)));
        acc[0][m] = __builtin_amdgcn_mfma_f32_16x16x32_bf16(afr[0][kk], bfr, acc[0][m], 0, 0, 0);
        acc[1][m] = __builtin_amdgcn_mfma_f32_16x16x32_bf16(afr[1][kk], bfr, acc[1][m], 0, 0, 0);
      }
    }

#pragma unroll
    for (int nt = 0; nt < 2; ++nt) {
      if (n_st[nt] < N_ENT) {
#pragma unroll
        for (int m = 0; m < 4; ++m) {
          int b = b0 + m * 16 + l16;
          float4 o = {acc[nt][m][0] + bv[nt].x, acc[nt][m][1] + bv[nt].y,
                      acc[nt][m][2] + bv[nt].z, acc[nt][m][3] + bv[nt].w};
          *(float4*)&out[(size_t)b * N_ENT + n_st[nt]] = o;
        }
      }
    }
    __syncthreads();  // LDS reads done before next stage overwrites
  }
}

extern "C" void kernel_launch(void* const* d_in, const int* in_sizes, int n_in,
                              void* d_out, int out_size, void* d_ws, size_t ws_size,
                              hipStream_t stream) {
  const float* entity    = (const float*)d_in[0];
  const float* edge_val  = (const float*)d_in[1];
  const float* gnn_W     = (const float*)d_in[2];
  const float* gnn_b     = (const float*)d_in[3];
  const float* rel_table = (const float*)d_in[4];
  const float* fc_W      = (const float*)d_in[5];
  const float* fc_b      = (const float*)d_in[6];
  const int* edge_row    = (const int*)d_in[7];
  const int* edge_col    = (const int*)d_in[8];
  const int* head_idx    = (const int*)d_in[9];
  const int* rel_ids     = (const int*)d_in[10];
  float* out = (float*)d_out;

  char* ws = (char*)d_ws;
  size_t off = 0;
  auto alloc = [&](size_t bytes) -> void* {
    void* p = ws + off;
    off = (off + bytes + 255) & ~(size_t)255;
    return p;
  };
  int* counts   = (int*)alloc((size_t)N_NODES * 4);
  int* row_ptr  = (int*)alloc((size_t)(N_NODES + 1) * 4);
  int* cursor   = (int*)alloc((size_t)N_NODES * 4);
  int* bsum     = (int*)alloc((size_t)256 * 4);
  int* col_s    = (int*)alloc((size_t)N_EDGES * 4);
  float* val_s  = (float*)alloc((size_t)N_EDGES * 4);
  unsigned short* xA    = (unsigned short*)alloc((size_t)N_NODES * D * 2);
  unsigned short* xB    = (unsigned short*)alloc((size_t)N_NODES * D * 2);
  unsigned short* entbf = (unsigned short*)alloc((size_t)N_NODES * D * 2);
  unsigned short* ebf   = (unsigned short*)alloc((size_t)BATCH * KDIM * 2);
  unsigned short* Wt    = (unsigned short*)alloc((size_t)(N_ENT + 256) * KDIM * 2);  // pad rows
  unsigned short* Wt5   = (unsigned short*)alloc((size_t)N_LAYERS * D * D * 2);

  // CSR build (row structure is layer-invariant)
  zero_i32<<<(N_NODES + 255) / 256, 256, 0, stream>>>(counts, N_NODES);
  hist_kernel<<<1024, 256, 0, stream>>>(edge_row, counts);
  scan1_kernel<<<SCAN_BLOCKS, 256, 0, stream>>>(counts, row_ptr, bsum);
  scan2_kernel<<<1, 256, 0, stream>>>(bsum);
  scan3_kernel<<<SCAN_BLOCKS, 256, 0, stream>>>(counts, bsum, row_ptr, cursor);
  scatter_kernel<<<1024, 256, 0, stream>>>(edge_row, edge_col, edge_val, cursor, col_s, val_s);

  // conversions
  tobf16_kernel<<<(N_NODES * D / 8 + 255) / 256, 256, 0, stream>>>(entity, entbf, N_NODES * D / 8);
  wconv_kernel<<<(N_LAYERS * D * D + 255) / 256, 256, 0, stream>>>(gnn_W, Wt5);

  // 5 fused GNN layers, ping-pong buffers
  for (int layer = 0; layer < N_LAYERS; ++layer) {
    const unsigned short* xin = (layer == 0) ? entbf : ((layer & 1) ? xA : xB);
    unsigned short* yout = (layer & 1) ? xB : xA;
    layer_fused<<<(N_NODES + 63) / 64, 256, 0, stream>>>(xin, row_ptr, col_s, val_s,
                                                         Wt5 + (size_t)layer * D * D,
                                                         gnn_b + (size_t)layer * D, yout);
  }

  // FC weight transpose + embed gather (final features in xA)
  dim3 wtg((N_ENT + 255) / 256, KDIM / 8);
  wt_kernel<<<wtg, 256, 0, stream>>>(fc_W, Wt);
  gather_bf16<<<BATCH, KDIM, 0, stream>>>(xA, rel_table, head_idx, rel_ids, ebf);

  // FC: grid (n-tiles, b-halves)
  dim3 fcg((N_ENT + FC_NT - 1) / FC_NT, 2);
  fc_mfma<<<fcg, 256, 0, stream>>>(ebf, Wt, fc_b, out);
}